// Round 3
// baseline (369.053 us; speedup 1.0000x reference)
//
#include <hip/hip_runtime.h>
#include <cstdint>

// Problem constants (fixed by the reference): B=8, N=16384, D=64, P=100.
#define NB    8
#define NN    16384
#define ND    64
#define NP    100
#define NPP   128          // theta rows padded (zeros) for MFMA K/N tiling
#define ST    1024         // sort threads per block (16 waves)
#define SE    16           // elements per sort thread (16384/1024)

typedef __attribute__((ext_vector_type(8))) short short8;   // 8 bf16 (4 VGPRs)
typedef __attribute__((ext_vector_type(4))) float f32x4;    // MFMA C/D

// ---------- bf16 convert (RNE) ----------
__device__ __forceinline__ short bf16c(float f) {
  uint32_t u = __float_as_uint(f);
  u = u + 0x7FFFu + ((u >> 16) & 1u);
  return (short)(u >> 16);
}

// ---------- sortable-key transforms ----------
__device__ __forceinline__ uint32_t f2s_u(uint32_t s) {
  return s ^ (((uint32_t)((int32_t)s >> 31)) | 0x80000000u);
}
__device__ __forceinline__ float s2f(uint32_t u) {
  uint32_t m = (u & 0x80000000u) ? 0x80000000u : 0xFFFFFFFFu;
  return __uint_as_float(u ^ m);
}

// LDS bank swizzle on word index (16B-contiguity-preserving)
__device__ __forceinline__ uint32_t swz(uint32_t w) {
  return w ^ ((w >> 3) & 0x1Cu);
}

// One LSD radix pass on 3-bit digit at shift sh, stable, in-place in S[16384].
// 16 waves. 2 barriers/pass: the cross-wave scan is computed REDUNDANTLY by
// every wave (lanes that would otherwise idle-wait), removing the old
// single-wave scan section and its trailing barrier.
__device__ __forceinline__ void radix_pass(uint32_t (&k)[SE], uint32_t* S,
                                           uint32_t* WG, int tid, int sh,
                                           bool first) {
  const int lane = tid & 63;
  const int wave = tid >> 6;

  if (!first) {
#pragma unroll
    for (int q = 0; q < 4; q++) {
      uint32_t wb = ((uint32_t)tid << 4) + ((uint32_t)q << 2);
      uint4 v = *(const uint4*)(S + (wb ^ ((wb >> 3) & 0x1Cu)));
      k[4 * q + 0] = v.x; k[4 * q + 1] = v.y;
      k[4 * q + 2] = v.z; k[4 * q + 3] = v.w;
    }
  }

  // per-thread digit histogram packed 8 x 8-bit (counts <= 16)
  uint64_t c = 0;
#pragma unroll
  for (int e = 0; e < SE; e++) {
    uint32_t d = (k[e] >> sh) & 7u;
    c += 1ull << (d << 3);
  }

  uint32_t lo = (uint32_t)c, hi = (uint32_t)(c >> 32);
  uint32_t h[4], o[4];
  h[0] = (lo & 0xFFu) | ((lo & 0xFF00u) << 8);
  h[1] = ((lo >> 16) & 0xFFu) | ((lo >> 24) << 16);
  h[2] = (hi & 0xFFu) | ((hi & 0xFF00u) << 8);
  h[3] = ((hi >> 16) & 0xFFu) | ((hi >> 24) << 16);
#pragma unroll
  for (int i = 0; i < 4; i++) o[i] = h[i];

  // wave-level inclusive scan of packed (2x16-bit) counts
#pragma unroll
  for (int off = 1; off <= 32; off <<= 1) {
#pragma unroll
    for (int i = 0; i < 4; i++) {
      uint32_t t = __shfl_up(h[i], (unsigned)off, 64);
      if (lane >= off) h[i] += t;
    }
  }

  if (lane == 63) {
#pragma unroll
    for (int i = 0; i < 4; i++) WG[(wave << 2) + i] = h[i];
  }
  __syncthreads();

  // redundant per-wave block scan over the 64 WG entries (16 waves x 4 words).
  // Every wave computes the identical result; own bases fetched via shfl.
  {
    uint32_t v = WG[lane];
    uint32_t own = v;
#pragma unroll
    for (int off = 4; off <= 32; off <<= 1) {
      uint32_t t = __shfl_up(v, (unsigned)off, 64);
      if (lane >= off) v += t;
    }
    uint32_t wexcl = v - own;                       // excl across waves, same word
    uint32_t grand = __shfl(v, 60 + (lane & 3), 64); // wave-15 inclusive = totals
    uint32_t gl = grand & 0xFFFFu, gh = grand >> 16;
    uint32_t ps = gl + gh, pincl = ps;
#pragma unroll
    for (int off2 = 1; off2 <= 2; off2 <<= 1) {
      uint32_t t = __shfl_up(pincl, (unsigned)off2, 64);
      if ((lane & 3) >= off2) pincl += t;
    }
    uint32_t pexcl = pincl - ps;                    // digit base for this word pair
    uint32_t fin = (pexcl + (wexcl & 0xFFFFu)) |
                   ((pexcl + gl + (wexcl >> 16)) << 16);
    const int wb4 = wave << 2;
    uint32_t w0 = __shfl(fin, wb4 + 0, 64);
    uint32_t w1 = __shfl(fin, wb4 + 1, 64);
    uint32_t w2 = __shfl(fin, wb4 + 2, 64);
    uint32_t w3 = __shfl(fin, wb4 + 3, 64);
    h[0] = w0 + (h[0] - o[0]);
    h[1] = w1 + (h[1] - o[1]);
    h[2] = w2 + (h[2] - o[2]);
    h[3] = w3 + (h[3] - o[3]);
  }

  uint64_t pc0 = (uint64_t)h[0] | ((uint64_t)h[1] << 32);
  uint64_t pc1 = (uint64_t)h[2] | ((uint64_t)h[3] << 32);

#pragma unroll
  for (int e = 0; e < SE; e++) {
    uint32_t d = (k[e] >> sh) & 7u;
    uint32_t s16 = (d & 3u) << 4;
    bool lo4 = d < 4u;
    uint64_t t = lo4 ? pc0 : pc1;
    uint32_t pos = (uint32_t)(t >> s16) & 0xFFFFu;
    uint64_t inc = 1ull << s16;
    pc0 += lo4 ? inc : 0ull;
    pc1 += lo4 ? 0ull : inc;
    S[swz(pos)] = k[e];
  }
  __syncthreads();
}

__device__ __forceinline__ void radix18(uint32_t (&k)[SE], uint32_t* S,
                                        uint32_t* WG, int tid) {
  bool first = true;
  for (int sh = 14; sh < 32; sh += 3) {
    radix_pass(k, S, WG, tid, sh, first);
    first = false;
  }
}

// ---------- kernel 1: normalize theta rows -> bf16, zero-padded to 128 ------
__global__ void normalize_theta(const float* __restrict__ theta,
                                ushort* __restrict__ thb) {
  const int p = blockIdx.x, t = threadIdx.x;
  if (p < NP) {
    float v = theta[p * ND + t];
    float ss = v * v;
#pragma unroll
    for (int off = 32; off >= 1; off >>= 1) ss += __shfl_xor(ss, off, 64);
    thb[p * ND + t] = (ushort)bf16c(v * rsqrtf(ss));
  } else {
    thb[p * ND + t] = 0;
  }
}

// ---------- kernel 2: MFMA projection (x AND y per block) ----------
// C[m=bn][n=p] = sum_k srcrow[m][k]*theta[p][k].  One wave = 16-row M-tile x
// 7 p-tiles of 16, K=64 = 2 chained mfma_f32_16x16x32_bf16, done for BOTH
// x and y so theta fragment loads + address math amortize 2x.
__global__ __launch_bounds__(256) void project_mfma(
    const float* __restrict__ x, const float* __restrict__ y,
    const ushort* __restrict__ thb, float* __restrict__ xp,
    float* __restrict__ yp) {
  const int tid  = threadIdx.x;
  const int lane = tid & 63;
  const int quad = lane >> 4;
  const int mloc = lane & 15;
  const int wave = tid >> 6;

  const int m0 = blockIdx.x * 64 + wave * 16;   // 2048 blocks, 64 rows each
  const int b  = m0 >> 14;
  const int n0 = m0 & (NN - 1);

  const long abase = (long)(m0 + mloc) * ND + quad * 8;
  const float* apx = x + abase;
  const float* apy = y + abase;
  float4 xq0 = *(const float4*)(apx + 0);
  float4 xq1 = *(const float4*)(apx + 4);
  float4 xq2 = *(const float4*)(apx + 32);
  float4 xq3 = *(const float4*)(apx + 36);
  float4 yq0 = *(const float4*)(apy + 0);
  float4 yq1 = *(const float4*)(apy + 4);
  float4 yq2 = *(const float4*)(apy + 32);
  float4 yq3 = *(const float4*)(apy + 36);

  short8 ax0, ax1, ay0, ay1;
  ax0[0] = bf16c(xq0.x); ax0[1] = bf16c(xq0.y); ax0[2] = bf16c(xq0.z); ax0[3] = bf16c(xq0.w);
  ax0[4] = bf16c(xq1.x); ax0[5] = bf16c(xq1.y); ax0[6] = bf16c(xq1.z); ax0[7] = bf16c(xq1.w);
  ax1[0] = bf16c(xq2.x); ax1[1] = bf16c(xq2.y); ax1[2] = bf16c(xq2.z); ax1[3] = bf16c(xq2.w);
  ax1[4] = bf16c(xq3.x); ax1[5] = bf16c(xq3.y); ax1[6] = bf16c(xq3.z); ax1[7] = bf16c(xq3.w);
  ay0[0] = bf16c(yq0.x); ay0[1] = bf16c(yq0.y); ay0[2] = bf16c(yq0.z); ay0[3] = bf16c(yq0.w);
  ay0[4] = bf16c(yq1.x); ay0[5] = bf16c(yq1.y); ay0[6] = bf16c(yq1.z); ay0[7] = bf16c(yq1.w);
  ay1[0] = bf16c(yq2.x); ay1[1] = bf16c(yq2.y); ay1[2] = bf16c(yq2.z); ay1[3] = bf16c(yq2.w);
  ay1[4] = bf16c(yq3.x); ay1[5] = bf16c(yq3.y); ay1[6] = bf16c(yq3.z); ay1[7] = bf16c(yq3.w);

  const f32x4 zero = {0.f, 0.f, 0.f, 0.f};
#pragma unroll
  for (int t = 0; t < 7; t++) {
    const int p = t * 16 + mloc;
    const short8 b0 = *(const short8*)(thb + p * ND + quad * 8);
    const short8 b1 = *(const short8*)(thb + p * ND + 32 + quad * 8);
    f32x4 accx = __builtin_amdgcn_mfma_f32_16x16x32_bf16(ax0, b0, zero, 0, 0, 0);
    accx = __builtin_amdgcn_mfma_f32_16x16x32_bf16(ax1, b1, accx, 0, 0, 0);
    f32x4 accy = __builtin_amdgcn_mfma_f32_16x16x32_bf16(ay0, b0, zero, 0, 0, 0);
    accy = __builtin_amdgcn_mfma_f32_16x16x32_bf16(ay1, b1, accy, 0, 0, 0);
    if (t < 6 || mloc < (NP - 96)) {
      const long off = ((long)b * NP + p) * NN + n0 + quad * 4;
      *(f32x4*)(xp + off) = accx;   // rows quad*4+r are consecutive n -> float4
      *(f32x4*)(yp + off) = accy;
    }
  }
}

// ---------- kernel 3: per-(b,p) radix-sort y, rank x, write diff ----------
__global__ __launch_bounds__(ST, 8) void sort_diff_kernel(
    const float* __restrict__ xp, float* __restrict__ yp) {
  __shared__ uint32_t S[NN];    // 64 KB
  __shared__ uint32_t WG[64];
  const int tid = threadIdx.x;
  const long sbase = (long)blockIdx.x * NN;
  uint32_t k[SE];

  {
    const uint4* yg = (const uint4*)(yp + sbase) + (tid << 2);
#pragma unroll
    for (int q = 0; q < 4; q++) {
      uint4 v = yg[q];
      k[4 * q + 0] = f2s_u(v.x); k[4 * q + 1] = f2s_u(v.y);
      k[4 * q + 2] = f2s_u(v.z); k[4 * q + 3] = f2s_u(v.w);
    }
  }
  radix18(k, S, WG, tid);

  float ys[SE];
#pragma unroll
  for (int q = 0; q < 4; q++) {
    uint32_t wb = ((uint32_t)tid << 4) + ((uint32_t)q << 2);
    uint4 v = *(const uint4*)(S + (wb ^ ((wb >> 3) & 0x1Cu)));
    ys[4 * q + 0] = s2f(v.x); ys[4 * q + 1] = s2f(v.y);
    ys[4 * q + 2] = s2f(v.z); ys[4 * q + 3] = s2f(v.w);
  }

  {
    const uint4* xg = (const uint4*)(xp + sbase) + (tid << 2);
#pragma unroll
    for (int q = 0; q < 4; q++) {
      uint4 v = xg[q];
      uint32_t g = ((uint32_t)tid << 4) + (uint32_t)(q << 2);
      k[4 * q + 0] = (f2s_u(v.x) & 0xFFFFC000u) | (g + 0);
      k[4 * q + 1] = (f2s_u(v.y) & 0xFFFFC000u) | (g + 1);
      k[4 * q + 2] = (f2s_u(v.z) & 0xFFFFC000u) | (g + 2);
      k[4 * q + 3] = (f2s_u(v.w) & 0xFFFFC000u) | (g + 3);
    }
  }
  radix18(k, S, WG, tid);

#pragma unroll
  for (int q = 0; q < 4; q++) {
    uint32_t wb = ((uint32_t)tid << 4) + ((uint32_t)q << 2);
    uint4 v = *(const uint4*)(S + (wb ^ ((wb >> 3) & 0x1Cu)));
    k[4 * q + 0] = v.x & 0x3FFFu; k[4 * q + 1] = v.y & 0x3FFFu;
    k[4 * q + 2] = v.z & 0x3FFFu; k[4 * q + 3] = v.w & 0x3FFFu;
  }
  __syncthreads();

#pragma unroll
  for (int e = 0; e < SE; e++) {
    S[swz(k[e])] = __float_as_uint(ys[e]);
  }
  __syncthreads();

  const uint4* xg = (const uint4*)(xp + sbase) + (tid << 2);
  float4* og = (float4*)(yp + sbase) + (tid << 2);
#pragma unroll
  for (int q = 0; q < 4; q++) {
    uint32_t wb = ((uint32_t)tid << 4) + ((uint32_t)q << 2);
    uint4 v = *(const uint4*)(S + (wb ^ ((wb >> 3) & 0x1Cu)));
    uint4 xb = xg[q];
    float4 o;
    o.x = __uint_as_float(v.x) - __uint_as_float(xb.x);
    o.y = __uint_as_float(v.y) - __uint_as_float(xb.y);
    o.z = __uint_as_float(v.z) - __uint_as_float(xb.z);
    o.w = __uint_as_float(v.w) - __uint_as_float(xb.w);
    og[q] = o;
  }
}

// ---------- kernel 4: MFMA combine ----------
__global__ __launch_bounds__(256) void combine_mfma(
    const float* __restrict__ x, const float* __restrict__ diff,
    const ushort* __restrict__ thb, float* __restrict__ out) {
  const int tid  = threadIdx.x;
  const int lane = tid & 63;
  const int quad = lane >> 4;
  const int mloc = lane & 15;
  const int wave = tid >> 6;

  const int m0 = blockIdx.x * 64 + wave * 16;   // wave's first global row
  const int b  = m0 >> 14;
  const int n0 = m0 & (NN - 1);

  const float* dbase = diff + ((long)b * NP) * NN + n0 + mloc;
  short8 a[4];
#pragma unroll
  for (int kf = 0; kf < 4; kf++) {
#pragma unroll
    for (int j = 0; j < 8; j++) {
      const int p = kf * 32 + quad * 8 + j;
      const float v = (p < NP) ? dbase[(long)p * NN] : 0.0f;
      a[kf][j] = bf16c(v);
    }
  }

  const float inv = 1.0f / (float)NP;
  const f32x4 zero = {0.f, 0.f, 0.f, 0.f};
#pragma unroll
  for (int t = 0; t < 4; t++) {
    const int d = t * 16 + mloc;
    f32x4 acc = zero;
#pragma unroll
    for (int kf = 0; kf < 4; kf++) {
      short8 bf;
#pragma unroll
      for (int j = 0; j < 8; j++) {
        const int p = kf * 32 + quad * 8 + j;
        bf[j] = (short)thb[p * ND + d];
      }
      acc = __builtin_amdgcn_mfma_f32_16x16x32_bf16(a[kf], bf, acc, 0, 0, 0);
    }
#pragma unroll
    for (int r = 0; r < 4; r++) {
      const long off = (long)(m0 + quad * 4 + r) * ND + d;
      out[off] = x[off] + acc[r] * inv;
    }
  }
}

extern "C" void kernel_launch(void* const* d_in, const int* in_sizes, int n_in,
                              void* d_out, int out_size, void* d_ws, size_t ws_size,
                              hipStream_t stream) {
  const float* x     = (const float*)d_in[0];
  const float* y     = (const float*)d_in[1];
  const float* theta = (const float*)d_in[2];
  float* out = (float*)d_out;

  // workspace: [thb bf16 128x64: 16KB, pad 32KB][xp 52.4MB][yp/diff 52.4MB]
  ushort* thb = (ushort*)d_ws;
  float* xp = (float*)((char*)d_ws + (1 << 15));
  float* yp = xp + (size_t)NB * NP * NN;

  normalize_theta<<<dim3(NPP), dim3(ND), 0, stream>>>(theta, thb);
  project_mfma<<<dim3((NB * NN) / 64), dim3(256), 0, stream>>>(x, y, thb, xp, yp);
  sort_diff_kernel<<<dim3(NB * NP), dim3(ST), 0, stream>>>(xp, yp);
  combine_mfma<<<dim3((NB * NN) / 64), dim3(256), 0, stream>>>(x, yp, thb, out);
}

// Round 4
// 351.752 us; speedup vs baseline: 1.0492x; 1.0492x over previous
//
#include <hip/hip_runtime.h>
#include <cstdint>

// Problem constants (fixed by the reference): B=8, N=16384, D=64, P=100.
#define NB    8
#define NN    16384
#define ND    64
#define NP    100
#define NPP   128          // theta rows padded (zeros) for MFMA K/N tiling
#define ST    1024         // sort threads per block (16 waves)
#define SE    16           // elements per sort thread (16384/1024)

typedef __attribute__((ext_vector_type(8))) short short8;   // 8 bf16 (4 VGPRs)
typedef __attribute__((ext_vector_type(4))) float f32x4;    // MFMA C/D

// ---------- bf16 convert (RNE) ----------
__device__ __forceinline__ short bf16c(float f) {
  uint32_t u = __float_as_uint(f);
  u = u + 0x7FFFu + ((u >> 16) & 1u);
  return (short)(u >> 16);
}

// ---------- sortable-key transforms ----------
__device__ __forceinline__ uint32_t f2s_u(uint32_t s) {
  return s ^ (((uint32_t)((int32_t)s >> 31)) | 0x80000000u);
}
__device__ __forceinline__ float s2f(uint32_t u) {
  uint32_t m = (u & 0x80000000u) ? 0x80000000u : 0xFFFFFFFFu;
  return __uint_as_float(u ^ m);
}

// LDS bank swizzle on word index (16B-contiguity-preserving)
__device__ __forceinline__ uint32_t swz(uint32_t w) {
  return w ^ ((w >> 3) & 0x1Cu);
}

// One LSD radix pass on 3-bit digit at shift sh, stable, in-place in S[16384].
// 16 waves: per-wave packed scan + single-wave 64-entry block scan in WG.
// NOTE: the single-wave scan + barrier is CHEAPER than a redundant all-wave
// shuffle scan (measured: +9% regression) because __shfl -> ds_bpermute
// rides the LDS pipe on CDNA.
__device__ __forceinline__ void radix_pass(uint32_t (&k)[SE], uint32_t* S,
                                           uint32_t* WG, int tid, int sh,
                                           bool first) {
  const int lane = tid & 63;
  const int wave = tid >> 6;

  if (!first) {
#pragma unroll
    for (int q = 0; q < 4; q++) {
      uint32_t wb = ((uint32_t)tid << 4) + ((uint32_t)q << 2);
      uint4 v = *(const uint4*)(S + (wb ^ ((wb >> 3) & 0x1Cu)));
      k[4 * q + 0] = v.x; k[4 * q + 1] = v.y;
      k[4 * q + 2] = v.z; k[4 * q + 3] = v.w;
    }
  }

  // per-thread digit histogram packed 8 x 8-bit (counts <= 16)
  uint64_t c = 0;
#pragma unroll
  for (int e = 0; e < SE; e++) {
    uint32_t d = (k[e] >> sh) & 7u;
    c += 1ull << (d << 3);
  }

  uint32_t lo = (uint32_t)c, hi = (uint32_t)(c >> 32);
  uint32_t h[4], o[4];
  h[0] = (lo & 0xFFu) | ((lo & 0xFF00u) << 8);
  h[1] = ((lo >> 16) & 0xFFu) | ((lo >> 24) << 16);
  h[2] = (hi & 0xFFu) | ((hi & 0xFF00u) << 8);
  h[3] = ((hi >> 16) & 0xFFu) | ((hi >> 24) << 16);
#pragma unroll
  for (int i = 0; i < 4; i++) o[i] = h[i];

  // wave-level inclusive scan of packed (2x16-bit) counts
#pragma unroll
  for (int off = 1; off <= 32; off <<= 1) {
#pragma unroll
    for (int i = 0; i < 4; i++) {
      uint32_t t = __shfl_up(h[i], (unsigned)off, 64);
      if (lane >= off) h[i] += t;
    }
  }

  if (lane == 63) {
#pragma unroll
    for (int i = 0; i < 4; i++) WG[(wave << 2) + i] = h[i];
  }
  __syncthreads();

  // block scan across 16 waves x 4 packed words (64 entries, one wave)
  if (tid < 64) {
    uint32_t v = WG[tid];
    uint32_t own = v;
#pragma unroll
    for (int off = 4; off <= 32; off <<= 1) {
      uint32_t t = __shfl_up(v, (unsigned)off, 64);
      if (tid >= off) v += t;
    }
    uint32_t wexcl = v - own;                       // excl across waves, same word
    uint32_t grand = __shfl(v, 60 + (tid & 3), 64); // wave-15 inclusive = totals
    uint32_t gl = grand & 0xFFFFu, gh = grand >> 16;
    uint32_t ps = gl + gh, pincl = ps;
#pragma unroll
    for (int off = 1; off <= 2; off <<= 1) {
      uint32_t t = __shfl_up(pincl, (unsigned)off, 64);
      if ((tid & 3) >= off) pincl += t;
    }
    uint32_t pexcl = pincl - ps;                    // digit base for this word pair
    uint32_t g0 = pexcl + (wexcl & 0xFFFFu);
    uint32_t g1 = pexcl + gl + (wexcl >> 16);
    WG[tid] = g0 | (g1 << 16);
  }
  __syncthreads();

  uint32_t p0 = WG[(wave << 2) + 0] + (h[0] - o[0]);
  uint32_t p1 = WG[(wave << 2) + 1] + (h[1] - o[1]);
  uint32_t p2 = WG[(wave << 2) + 2] + (h[2] - o[2]);
  uint32_t p3 = WG[(wave << 2) + 3] + (h[3] - o[3]);
  uint64_t pc0 = (uint64_t)p0 | ((uint64_t)p1 << 32);
  uint64_t pc1 = (uint64_t)p2 | ((uint64_t)p3 << 32);

#pragma unroll
  for (int e = 0; e < SE; e++) {
    uint32_t d = (k[e] >> sh) & 7u;
    uint32_t s16 = (d & 3u) << 4;
    bool lo4 = d < 4u;
    uint64_t t = lo4 ? pc0 : pc1;
    uint32_t pos = (uint32_t)(t >> s16) & 0xFFFFu;
    uint64_t inc = 1ull << s16;
    pc0 += lo4 ? inc : 0ull;
    pc1 += lo4 ? 0ull : inc;
    S[swz(pos)] = k[e];
  }
  __syncthreads();
}

__device__ __forceinline__ void radix18(uint32_t (&k)[SE], uint32_t* S,
                                        uint32_t* WG, int tid) {
  bool first = true;
  for (int sh = 14; sh < 32; sh += 3) {
    radix_pass(k, S, WG, tid, sh, first);
    first = false;
  }
}

// ---------- kernel 1: normalize theta rows -> bf16, zero-padded to 128 ------
__global__ void normalize_theta(const float* __restrict__ theta,
                                ushort* __restrict__ thb) {
  const int p = blockIdx.x, t = threadIdx.x;
  if (p < NP) {
    float v = theta[p * ND + t];
    float ss = v * v;
#pragma unroll
    for (int off = 32; off >= 1; off >>= 1) ss += __shfl_xor(ss, off, 64);
    thb[p * ND + t] = (ushort)bf16c(v * rsqrtf(ss));
  } else {
    thb[p * ND + t] = 0;
  }
}

// ---------- kernel 2: MFMA projection (x AND y per block) ----------
// C[m=bn][n=p] = sum_k srcrow[m][k]*theta[p][k].  One wave = 16-row M-tile x
// 7 p-tiles of 16, K=64 = 2 chained mfma_f32_16x16x32_bf16, done for BOTH
// x and y so theta fragment loads + address math amortize 2x.
__global__ __launch_bounds__(256) void project_mfma(
    const float* __restrict__ x, const float* __restrict__ y,
    const ushort* __restrict__ thb, float* __restrict__ xp,
    float* __restrict__ yp) {
  const int tid  = threadIdx.x;
  const int lane = tid & 63;
  const int quad = lane >> 4;
  const int mloc = lane & 15;
  const int wave = tid >> 6;

  const int m0 = blockIdx.x * 64 + wave * 16;   // 2048 blocks, 64 rows each
  const int b  = m0 >> 14;
  const int n0 = m0 & (NN - 1);

  const long abase = (long)(m0 + mloc) * ND + quad * 8;
  const float* apx = x + abase;
  const float* apy = y + abase;
  float4 xq0 = *(const float4*)(apx + 0);
  float4 xq1 = *(const float4*)(apx + 4);
  float4 xq2 = *(const float4*)(apx + 32);
  float4 xq3 = *(const float4*)(apx + 36);
  float4 yq0 = *(const float4*)(apy + 0);
  float4 yq1 = *(const float4*)(apy + 4);
  float4 yq2 = *(const float4*)(apy + 32);
  float4 yq3 = *(const float4*)(apy + 36);

  short8 ax0, ax1, ay0, ay1;
  ax0[0] = bf16c(xq0.x); ax0[1] = bf16c(xq0.y); ax0[2] = bf16c(xq0.z); ax0[3] = bf16c(xq0.w);
  ax0[4] = bf16c(xq1.x); ax0[5] = bf16c(xq1.y); ax0[6] = bf16c(xq1.z); ax0[7] = bf16c(xq1.w);
  ax1[0] = bf16c(xq2.x); ax1[1] = bf16c(xq2.y); ax1[2] = bf16c(xq2.z); ax1[3] = bf16c(xq2.w);
  ax1[4] = bf16c(xq3.x); ax1[5] = bf16c(xq3.y); ax1[6] = bf16c(xq3.z); ax1[7] = bf16c(xq3.w);
  ay0[0] = bf16c(yq0.x); ay0[1] = bf16c(yq0.y); ay0[2] = bf16c(yq0.z); ay0[3] = bf16c(yq0.w);
  ay0[4] = bf16c(yq1.x); ay0[5] = bf16c(yq1.y); ay0[6] = bf16c(yq1.z); ay0[7] = bf16c(yq1.w);
  ay1[0] = bf16c(yq2.x); ay1[1] = bf16c(yq2.y); ay1[2] = bf16c(yq2.z); ay1[3] = bf16c(yq2.w);
  ay1[4] = bf16c(yq3.x); ay1[5] = bf16c(yq3.y); ay1[6] = bf16c(yq3.z); ay1[7] = bf16c(yq3.w);

  const f32x4 zero = {0.f, 0.f, 0.f, 0.f};
#pragma unroll
  for (int t = 0; t < 7; t++) {
    const int p = t * 16 + mloc;
    const short8 b0 = *(const short8*)(thb + p * ND + quad * 8);
    const short8 b1 = *(const short8*)(thb + p * ND + 32 + quad * 8);
    f32x4 accx = __builtin_amdgcn_mfma_f32_16x16x32_bf16(ax0, b0, zero, 0, 0, 0);
    accx = __builtin_amdgcn_mfma_f32_16x16x32_bf16(ax1, b1, accx, 0, 0, 0);
    f32x4 accy = __builtin_amdgcn_mfma_f32_16x16x32_bf16(ay0, b0, zero, 0, 0, 0);
    accy = __builtin_amdgcn_mfma_f32_16x16x32_bf16(ay1, b1, accy, 0, 0, 0);
    if (t < 6 || mloc < (NP - 96)) {
      const long off = ((long)b * NP + p) * NN + n0 + quad * 4;
      *(f32x4*)(xp + off) = accx;   // rows quad*4+r are consecutive n -> float4
      *(f32x4*)(yp + off) = accy;
    }
  }
}

// ---------- kernel 3: per-(b,p) radix-sort y, rank x, write diff ----------
__global__ __launch_bounds__(ST, 8) void sort_diff_kernel(
    const float* __restrict__ xp, float* __restrict__ yp) {
  __shared__ uint32_t S[NN];    // 64 KB
  __shared__ uint32_t WG[64];
  const int tid = threadIdx.x;
  const long sbase = (long)blockIdx.x * NN;
  uint32_t k[SE];

  {
    const uint4* yg = (const uint4*)(yp + sbase) + (tid << 2);
#pragma unroll
    for (int q = 0; q < 4; q++) {
      uint4 v = yg[q];
      k[4 * q + 0] = f2s_u(v.x); k[4 * q + 1] = f2s_u(v.y);
      k[4 * q + 2] = f2s_u(v.z); k[4 * q + 3] = f2s_u(v.w);
    }
  }
  radix18(k, S, WG, tid);

  float ys[SE];
#pragma unroll
  for (int q = 0; q < 4; q++) {
    uint32_t wb = ((uint32_t)tid << 4) + ((uint32_t)q << 2);
    uint4 v = *(const uint4*)(S + (wb ^ ((wb >> 3) & 0x1Cu)));
    ys[4 * q + 0] = s2f(v.x); ys[4 * q + 1] = s2f(v.y);
    ys[4 * q + 2] = s2f(v.z); ys[4 * q + 3] = s2f(v.w);
  }

  {
    const uint4* xg = (const uint4*)(xp + sbase) + (tid << 2);
#pragma unroll
    for (int q = 0; q < 4; q++) {
      uint4 v = xg[q];
      uint32_t g = ((uint32_t)tid << 4) + (uint32_t)(q << 2);
      k[4 * q + 0] = (f2s_u(v.x) & 0xFFFFC000u) | (g + 0);
      k[4 * q + 1] = (f2s_u(v.y) & 0xFFFFC000u) | (g + 1);
      k[4 * q + 2] = (f2s_u(v.z) & 0xFFFFC000u) | (g + 2);
      k[4 * q + 3] = (f2s_u(v.w) & 0xFFFFC000u) | (g + 3);
    }
  }
  radix18(k, S, WG, tid);

#pragma unroll
  for (int q = 0; q < 4; q++) {
    uint32_t wb = ((uint32_t)tid << 4) + ((uint32_t)q << 2);
    uint4 v = *(const uint4*)(S + (wb ^ ((wb >> 3) & 0x1Cu)));
    k[4 * q + 0] = v.x & 0x3FFFu; k[4 * q + 1] = v.y & 0x3FFFu;
    k[4 * q + 2] = v.z & 0x3FFFu; k[4 * q + 3] = v.w & 0x3FFFu;
  }
  __syncthreads();

#pragma unroll
  for (int e = 0; e < SE; e++) {
    S[swz(k[e])] = __float_as_uint(ys[e]);
  }
  __syncthreads();

  const uint4* xg = (const uint4*)(xp + sbase) + (tid << 2);
  float4* og = (float4*)(yp + sbase) + (tid << 2);
#pragma unroll
  for (int q = 0; q < 4; q++) {
    uint32_t wb = ((uint32_t)tid << 4) + ((uint32_t)q << 2);
    uint4 v = *(const uint4*)(S + (wb ^ ((wb >> 3) & 0x1Cu)));
    uint4 xb = xg[q];
    float4 o;
    o.x = __uint_as_float(v.x) - __uint_as_float(xb.x);
    o.y = __uint_as_float(v.y) - __uint_as_float(xb.y);
    o.z = __uint_as_float(v.z) - __uint_as_float(xb.z);
    o.w = __uint_as_float(v.w) - __uint_as_float(xb.w);
    og[q] = o;
  }
}

// ---------- kernel 4: MFMA combine ----------
__global__ __launch_bounds__(256) void combine_mfma(
    const float* __restrict__ x, const float* __restrict__ diff,
    const ushort* __restrict__ thb, float* __restrict__ out) {
  const int tid  = threadIdx.x;
  const int lane = tid & 63;
  const int quad = lane >> 4;
  const int mloc = lane & 15;
  const int wave = tid >> 6;

  const int m0 = blockIdx.x * 64 + wave * 16;   // wave's first global row
  const int b  = m0 >> 14;
  const int n0 = m0 & (NN - 1);

  const float* dbase = diff + ((long)b * NP) * NN + n0 + mloc;
  short8 a[4];
#pragma unroll
  for (int kf = 0; kf < 4; kf++) {
#pragma unroll
    for (int j = 0; j < 8; j++) {
      const int p = kf * 32 + quad * 8 + j;
      const float v = (p < NP) ? dbase[(long)p * NN] : 0.0f;
      a[kf][j] = bf16c(v);
    }
  }

  const float inv = 1.0f / (float)NP;
  const f32x4 zero = {0.f, 0.f, 0.f, 0.f};
#pragma unroll
  for (int t = 0; t < 4; t++) {
    const int d = t * 16 + mloc;
    f32x4 acc = zero;
#pragma unroll
    for (int kf = 0; kf < 4; kf++) {
      short8 bf;
#pragma unroll
      for (int j = 0; j < 8; j++) {
        const int p = kf * 32 + quad * 8 + j;
        bf[j] = (short)thb[p * ND + d];
      }
      acc = __builtin_amdgcn_mfma_f32_16x16x32_bf16(a[kf], bf, acc, 0, 0, 0);
    }
#pragma unroll
    for (int r = 0; r < 4; r++) {
      const long off = (long)(m0 + quad * 4 + r) * ND + d;
      out[off] = x[off] + acc[r] * inv;
    }
  }
}

extern "C" void kernel_launch(void* const* d_in, const int* in_sizes, int n_in,
                              void* d_out, int out_size, void* d_ws, size_t ws_size,
                              hipStream_t stream) {
  const float* x     = (const float*)d_in[0];
  const float* y     = (const float*)d_in[1];
  const float* theta = (const float*)d_in[2];
  float* out = (float*)d_out;

  // workspace: [thb bf16 128x64: 16KB, pad 32KB][xp 52.4MB][yp/diff 52.4MB]
  ushort* thb = (ushort*)d_ws;
  float* xp = (float*)((char*)d_ws + (1 << 15));
  float* yp = xp + (size_t)NB * NP * NN;

  normalize_theta<<<dim3(NPP), dim3(ND), 0, stream>>>(theta, thb);
  project_mfma<<<dim3((NB * NN) / 64), dim3(256), 0, stream>>>(x, y, thb, xp, yp);
  sort_diff_kernel<<<dim3(NB * NP), dim3(ST), 0, stream>>>(xp, yp);
  combine_mfma<<<dim3((NB * NN) / 64), dim3(256), 0, stream>>>(x, yp, thb, out);
}

// Round 5
// 348.013 us; speedup vs baseline: 1.0605x; 1.0107x over previous
//
#include <hip/hip_runtime.h>
#include <cstdint>

// Problem constants (fixed by the reference): B=8, N=16384, D=64, P=100.
#define NB    8
#define NN    16384
#define ND    64
#define NP    100
#define NPP   128          // theta rows padded (zeros) for MFMA K/N tiling
#define ST    1024         // sort threads per block (16 waves)
#define SE    16           // elements per sort thread (16384/1024)
#define TROW  72           // padded LDS row stride (ushorts) for project tiles

typedef __attribute__((ext_vector_type(8))) short short8;   // 8 bf16 (4 VGPRs)
typedef __attribute__((ext_vector_type(4))) float f32x4;    // MFMA C/D

// ---------- bf16 convert (RNE) ----------
__device__ __forceinline__ short bf16c(float f) {
  uint32_t u = __float_as_uint(f);
  u = u + 0x7FFFu + ((u >> 16) & 1u);
  return (short)(u >> 16);
}
__device__ __forceinline__ uint32_t bf16pk(float a, float b) {
  return (uint32_t)(ushort)bf16c(a) | ((uint32_t)(ushort)bf16c(b) << 16);
}

// ---------- sortable-key transforms ----------
__device__ __forceinline__ uint32_t f2s_u(uint32_t s) {
  return s ^ (((uint32_t)((int32_t)s >> 31)) | 0x80000000u);
}
__device__ __forceinline__ float s2f(uint32_t u) {
  uint32_t m = (u & 0x80000000u) ? 0x80000000u : 0xFFFFFFFFu;
  return __uint_as_float(u ^ m);
}

// LDS bank swizzle on word index (16B-contiguity-preserving)
__device__ __forceinline__ uint32_t swz(uint32_t w) {
  return w ^ ((w >> 3) & 0x1Cu);
}

// One LSD radix pass on 3-bit digit at shift sh, stable, in-place in S[16384].
// 16 waves: per-wave packed scan + single-wave 64-entry block scan in WG.
// NOTE: the single-wave scan + barrier is CHEAPER than a redundant all-wave
// shuffle scan (measured: +9% regression) because __shfl -> ds_bpermute
// rides the LDS pipe on CDNA.
__device__ __forceinline__ void radix_pass(uint32_t (&k)[SE], uint32_t* S,
                                           uint32_t* WG, int tid, int sh,
                                           bool first) {
  const int lane = tid & 63;
  const int wave = tid >> 6;

  if (!first) {
#pragma unroll
    for (int q = 0; q < 4; q++) {
      uint32_t wb = ((uint32_t)tid << 4) + ((uint32_t)q << 2);
      uint4 v = *(const uint4*)(S + (wb ^ ((wb >> 3) & 0x1Cu)));
      k[4 * q + 0] = v.x; k[4 * q + 1] = v.y;
      k[4 * q + 2] = v.z; k[4 * q + 3] = v.w;
    }
  }

  // per-thread digit histogram packed 8 x 8-bit (counts <= 16)
  uint64_t c = 0;
#pragma unroll
  for (int e = 0; e < SE; e++) {
    uint32_t d = (k[e] >> sh) & 7u;
    c += 1ull << (d << 3);
  }

  uint32_t lo = (uint32_t)c, hi = (uint32_t)(c >> 32);
  uint32_t h[4], o[4];
  h[0] = (lo & 0xFFu) | ((lo & 0xFF00u) << 8);
  h[1] = ((lo >> 16) & 0xFFu) | ((lo >> 24) << 16);
  h[2] = (hi & 0xFFu) | ((hi & 0xFF00u) << 8);
  h[3] = ((hi >> 16) & 0xFFu) | ((hi >> 24) << 16);
#pragma unroll
  for (int i = 0; i < 4; i++) o[i] = h[i];

  // wave-level inclusive scan of packed (2x16-bit) counts
#pragma unroll
  for (int off = 1; off <= 32; off <<= 1) {
#pragma unroll
    for (int i = 0; i < 4; i++) {
      uint32_t t = __shfl_up(h[i], (unsigned)off, 64);
      if (lane >= off) h[i] += t;
    }
  }

  if (lane == 63) {
#pragma unroll
    for (int i = 0; i < 4; i++) WG[(wave << 2) + i] = h[i];
  }
  __syncthreads();

  // block scan across 16 waves x 4 packed words (64 entries, one wave)
  if (tid < 64) {
    uint32_t v = WG[tid];
    uint32_t own = v;
#pragma unroll
    for (int off = 4; off <= 32; off <<= 1) {
      uint32_t t = __shfl_up(v, (unsigned)off, 64);
      if (tid >= off) v += t;
    }
    uint32_t wexcl = v - own;                       // excl across waves, same word
    uint32_t grand = __shfl(v, 60 + (tid & 3), 64); // wave-15 inclusive = totals
    uint32_t gl = grand & 0xFFFFu, gh = grand >> 16;
    uint32_t ps = gl + gh, pincl = ps;
#pragma unroll
    for (int off = 1; off <= 2; off <<= 1) {
      uint32_t t = __shfl_up(pincl, (unsigned)off, 64);
      if ((tid & 3) >= off) pincl += t;
    }
    uint32_t pexcl = pincl - ps;                    // digit base for this word pair
    uint32_t g0 = pexcl + (wexcl & 0xFFFFu);
    uint32_t g1 = pexcl + gl + (wexcl >> 16);
    WG[tid] = g0 | (g1 << 16);
  }
  __syncthreads();

  uint32_t p0 = WG[(wave << 2) + 0] + (h[0] - o[0]);
  uint32_t p1 = WG[(wave << 2) + 1] + (h[1] - o[1]);
  uint32_t p2 = WG[(wave << 2) + 2] + (h[2] - o[2]);
  uint32_t p3 = WG[(wave << 2) + 3] + (h[3] - o[3]);
  uint64_t pc0 = (uint64_t)p0 | ((uint64_t)p1 << 32);
  uint64_t pc1 = (uint64_t)p2 | ((uint64_t)p3 << 32);

#pragma unroll
  for (int e = 0; e < SE; e++) {
    uint32_t d = (k[e] >> sh) & 7u;
    uint32_t s16 = (d & 3u) << 4;
    bool lo4 = d < 4u;
    uint64_t t = lo4 ? pc0 : pc1;
    uint32_t pos = (uint32_t)(t >> s16) & 0xFFFFu;
    uint64_t inc = 1ull << s16;
    pc0 += lo4 ? inc : 0ull;
    pc1 += lo4 ? 0ull : inc;
    S[swz(pos)] = k[e];
  }
  __syncthreads();
}

__device__ __forceinline__ void radix18(uint32_t (&k)[SE], uint32_t* S,
                                        uint32_t* WG, int tid) {
  bool first = true;
  for (int sh = 14; sh < 32; sh += 3) {
    radix_pass(k, S, WG, tid, sh, first);
    first = false;
  }
}

// ---------- kernel 1: normalize theta -> bf16 thb [p][d] AND thbT [d][p] ----
__global__ void normalize_theta(const float* __restrict__ theta,
                                ushort* __restrict__ thb,
                                ushort* __restrict__ thbT) {
  const int p = blockIdx.x, t = threadIdx.x;
  ushort v16 = 0;
  if (p < NP) {
    float v = theta[p * ND + t];
    float ss = v * v;
#pragma unroll
    for (int off = 32; off >= 1; off >>= 1) ss += __shfl_xor(ss, off, 64);
    v16 = (ushort)bf16c(v * rsqrtf(ss));
  }
  thb[p * ND + t] = v16;
  thbT[t * NPP + p] = v16;
}

// ---------- kernel 2: MFMA projection (x AND y per block, LDS-staged) ------
// Stage the block's 64x64 fp32 tiles of x and y into LDS as bf16 via fully
// coalesced global loads (1KB/instr), then read MFMA A-fragments with
// ds_read_b128 (72-ushort padded rows -> 2-way bank aliasing = free).
__global__ __launch_bounds__(256) void project_mfma(
    const float* __restrict__ x, const float* __restrict__ y,
    const ushort* __restrict__ thb, float* __restrict__ xp,
    float* __restrict__ yp) {
  __shared__ ushort XT[64 * TROW];
  __shared__ ushort YT[64 * TROW];
  const int tid  = threadIdx.x;
  const int lane = tid & 63;
  const int quad = lane >> 4;
  const int mloc = lane & 15;
  const int wave = tid >> 6;

  const int m0 = blockIdx.x * 64 + wave * 16;   // 2048 blocks, 64 rows each
  const int b  = m0 >> 14;
  const int n0 = m0 & (NN - 1);

  // --- stage: 64 rows x 64 cols, 1024 float4 per matrix, 4 per thread ---
  {
    const float4* gx = (const float4*)(x + (long)blockIdx.x * 64 * ND);
    const float4* gy = (const float4*)(y + (long)blockIdx.x * 64 * ND);
#pragma unroll
    for (int i = 0; i < 4; i++) {
      const int f4 = tid + 256 * i;        // 0..1023
      const int row = f4 >> 4;             // 16 float4 per row
      const int c4  = f4 & 15;
      float4 vx = gx[f4];
      float4 vy = gy[f4];
      uint2 px, py;
      px.x = bf16pk(vx.x, vx.y); px.y = bf16pk(vx.z, vx.w);
      py.x = bf16pk(vy.x, vy.y); py.y = bf16pk(vy.z, vy.w);
      const int us = row * TROW + c4 * 4;  // ushort index, 8B-aligned
      *(uint2*)(XT + us) = px;
      *(uint2*)(YT + us) = py;
    }
  }
  __syncthreads();

  // --- fragments from LDS ---
  const int fr = wave * 16 + mloc;         // row within block tile
  const short8 ax0 = *(const short8*)(XT + fr * TROW + quad * 8);
  const short8 ax1 = *(const short8*)(XT + fr * TROW + 32 + quad * 8);
  const short8 ay0 = *(const short8*)(YT + fr * TROW + quad * 8);
  const short8 ay1 = *(const short8*)(YT + fr * TROW + 32 + quad * 8);

  const f32x4 zero = {0.f, 0.f, 0.f, 0.f};
#pragma unroll
  for (int t = 0; t < 7; t++) {
    const int p = t * 16 + mloc;
    const short8 b0 = *(const short8*)(thb + p * ND + quad * 8);
    const short8 b1 = *(const short8*)(thb + p * ND + 32 + quad * 8);
    f32x4 accx = __builtin_amdgcn_mfma_f32_16x16x32_bf16(ax0, b0, zero, 0, 0, 0);
    accx = __builtin_amdgcn_mfma_f32_16x16x32_bf16(ax1, b1, accx, 0, 0, 0);
    f32x4 accy = __builtin_amdgcn_mfma_f32_16x16x32_bf16(ay0, b0, zero, 0, 0, 0);
    accy = __builtin_amdgcn_mfma_f32_16x16x32_bf16(ay1, b1, accy, 0, 0, 0);
    if (t < 6 || mloc < (NP - 96)) {
      const long off = ((long)b * NP + p) * NN + n0 + quad * 4;
      *(f32x4*)(xp + off) = accx;   // rows quad*4+r are consecutive n -> float4
      *(f32x4*)(yp + off) = accy;
    }
  }
}

// ---------- kernel 3: per-(b,p) radix-sort y, rank x, write diff ----------
__global__ __launch_bounds__(ST, 8) void sort_diff_kernel(
    const float* __restrict__ xp, float* __restrict__ yp) {
  __shared__ uint32_t S[NN];    // 64 KB
  __shared__ uint32_t WG[64];
  const int tid = threadIdx.x;
  const long sbase = (long)blockIdx.x * NN;
  uint32_t k[SE];

  {
    const uint4* yg = (const uint4*)(yp + sbase) + (tid << 2);
#pragma unroll
    for (int q = 0; q < 4; q++) {
      uint4 v = yg[q];
      k[4 * q + 0] = f2s_u(v.x); k[4 * q + 1] = f2s_u(v.y);
      k[4 * q + 2] = f2s_u(v.z); k[4 * q + 3] = f2s_u(v.w);
    }
  }
  radix18(k, S, WG, tid);

  float ys[SE];
#pragma unroll
  for (int q = 0; q < 4; q++) {
    uint32_t wb = ((uint32_t)tid << 4) + ((uint32_t)q << 2);
    uint4 v = *(const uint4*)(S + (wb ^ ((wb >> 3) & 0x1Cu)));
    ys[4 * q + 0] = s2f(v.x); ys[4 * q + 1] = s2f(v.y);
    ys[4 * q + 2] = s2f(v.z); ys[4 * q + 3] = s2f(v.w);
  }

  {
    const uint4* xg = (const uint4*)(xp + sbase) + (tid << 2);
#pragma unroll
    for (int q = 0; q < 4; q++) {
      uint4 v = xg[q];
      uint32_t g = ((uint32_t)tid << 4) + (uint32_t)(q << 2);
      k[4 * q + 0] = (f2s_u(v.x) & 0xFFFFC000u) | (g + 0);
      k[4 * q + 1] = (f2s_u(v.y) & 0xFFFFC000u) | (g + 1);
      k[4 * q + 2] = (f2s_u(v.z) & 0xFFFFC000u) | (g + 2);
      k[4 * q + 3] = (f2s_u(v.w) & 0xFFFFC000u) | (g + 3);
    }
  }
  radix18(k, S, WG, tid);

#pragma unroll
  for (int q = 0; q < 4; q++) {
    uint32_t wb = ((uint32_t)tid << 4) + ((uint32_t)q << 2);
    uint4 v = *(const uint4*)(S + (wb ^ ((wb >> 3) & 0x1Cu)));
    k[4 * q + 0] = v.x & 0x3FFFu; k[4 * q + 1] = v.y & 0x3FFFu;
    k[4 * q + 2] = v.z & 0x3FFFu; k[4 * q + 3] = v.w & 0x3FFFu;
  }
  __syncthreads();

#pragma unroll
  for (int e = 0; e < SE; e++) {
    S[swz(k[e])] = __float_as_uint(ys[e]);
  }
  __syncthreads();

  const uint4* xg = (const uint4*)(xp + sbase) + (tid << 2);
  float4* og = (float4*)(yp + sbase) + (tid << 2);
#pragma unroll
  for (int q = 0; q < 4; q++) {
    uint32_t wb = ((uint32_t)tid << 4) + ((uint32_t)q << 2);
    uint4 v = *(const uint4*)(S + (wb ^ ((wb >> 3) & 0x1Cu)));
    uint4 xb = xg[q];
    float4 o;
    o.x = __uint_as_float(v.x) - __uint_as_float(xb.x);
    o.y = __uint_as_float(v.y) - __uint_as_float(xb.y);
    o.z = __uint_as_float(v.z) - __uint_as_float(xb.z);
    o.w = __uint_as_float(v.w) - __uint_as_float(xb.w);
    og[q] = o;
  }
}

// ---------- kernel 4: MFMA combine ----------
// B-fragments from thbT [d][p] -> single contiguous short8 per (t,kf).
__global__ __launch_bounds__(256) void combine_mfma(
    const float* __restrict__ x, const float* __restrict__ diff,
    const ushort* __restrict__ thbT, float* __restrict__ out) {
  const int tid  = threadIdx.x;
  const int lane = tid & 63;
  const int quad = lane >> 4;
  const int mloc = lane & 15;
  const int wave = tid >> 6;

  const int m0 = blockIdx.x * 64 + wave * 16;   // wave's first global row
  const int b  = m0 >> 14;
  const int n0 = m0 & (NN - 1);

  const float* dbase = diff + ((long)b * NP) * NN + n0 + mloc;
  short8 a[4];
#pragma unroll
  for (int kf = 0; kf < 4; kf++) {
#pragma unroll
    for (int j = 0; j < 8; j++) {
      const int p = kf * 32 + quad * 8 + j;
      const float v = (p < NP) ? dbase[(long)p * NN] : 0.0f;
      a[kf][j] = bf16c(v);
    }
  }

  const float inv = 1.0f / (float)NP;
  const f32x4 zero = {0.f, 0.f, 0.f, 0.f};
#pragma unroll
  for (int t = 0; t < 4; t++) {
    const int d = t * 16 + mloc;
    f32x4 acc = zero;
#pragma unroll
    for (int kf = 0; kf < 4; kf++) {
      const short8 bf = *(const short8*)(thbT + (long)d * NPP + kf * 32 + quad * 8);
      acc = __builtin_amdgcn_mfma_f32_16x16x32_bf16(a[kf], bf, acc, 0, 0, 0);
    }
#pragma unroll
    for (int r = 0; r < 4; r++) {
      const long off = (long)(m0 + quad * 4 + r) * ND + d;
      out[off] = x[off] + acc[r] * inv;
    }
  }
}

extern "C" void kernel_launch(void* const* d_in, const int* in_sizes, int n_in,
                              void* d_out, int out_size, void* d_ws, size_t ws_size,
                              hipStream_t stream) {
  const float* x     = (const float*)d_in[0];
  const float* y     = (const float*)d_in[1];
  const float* theta = (const float*)d_in[2];
  float* out = (float*)d_out;

  // workspace: [thb 16KB][thbT 16KB][xp 52.4MB][yp/diff 52.4MB]
  ushort* thb  = (ushort*)d_ws;
  ushort* thbT = thb + (size_t)NPP * ND;
  float* xp = (float*)((char*)d_ws + (1 << 15));
  float* yp = xp + (size_t)NB * NP * NN;

  normalize_theta<<<dim3(NPP), dim3(ND), 0, stream>>>(theta, thb, thbT);
  project_mfma<<<dim3((NB * NN) / 64), dim3(256), 0, stream>>>(x, y, thb, xp, yp);
  sort_diff_kernel<<<dim3(NB * NP), dim3(ST), 0, stream>>>(xp, yp);
  combine_mfma<<<dim3((NB * NN) / 64), dim3(256), 0, stream>>>(x, yp, thbT, out);
}